// Round 11
// baseline (109.019 us; speedup 1.0000x reference)
//
#include <hip/hip_runtime.h>

typedef __attribute__((ext_vector_type(4))) float f32x4;
typedef __attribute__((ext_vector_type(8))) short short8;

#define EPSF 1e-12f

__device__ __forceinline__ ushort bf16rne(float x) {
  uint u = __float_as_uint(x);
  u += 0x7fffu + ((u >> 16) & 1u);
  return (ushort)(u >> 16);
}
__device__ __forceinline__ float bf2f(ushort h) {
  return __uint_as_float(((uint)h) << 16);
}
// 8 floats -> hi/lo bf16 short8 pair (pure C: RNE hi, RNE residual lo)
__device__ __forceinline__ void cvt8hl(float4 v0, float4 v1, short8& h8, short8& l8) {
  float vals[8] = {v0.x, v0.y, v0.z, v0.w, v1.x, v1.y, v1.z, v1.w};
#pragma unroll
  for (int j = 0; j < 8; ++j) {
    ushort h = bf16rne(vals[j]);
    h8[j] = (short)h;
    l8[j] = (short)bf16rne(vals[j] - bf2f(h));
  }
}
__device__ __forceinline__ f32x4 mfma16(short8 a, short8 b, f32x4 c) {
  return __builtin_amdgcn_mfma_f32_16x16x32_bf16(a, b, c, 0, 0, 0);
}

// ---------------------------------------------------------------------------
// K0: W [512][64] f32 -> fragment-major W^T bf16 hi/lo:
//   ws2[plane][s2][mi][lane l][j]  (plane stride 32768 ushorts = 64KB)
//   element = W^T(k = mi*16 + (l&15), d = s2*32 + (l>>4)*8 + j)
// so a k1 wave's A-frag is ONE contiguous 1KB short8 load.
// ---------------------------------------------------------------------------
__global__ __launch_bounds__(256) void k0_wt(const float* __restrict__ W,
                                             ushort* __restrict__ ws2) {
  int k = blockIdx.x;  // 64
  int mi = k >> 4, l15k = k & 15;
  for (int task = threadIdx.x; task < 512; task += 256) {
    int dg8 = task >> 3, j = task & 7;   // dg8 = d>>3
    int d = dg8 * 8 + j;
    int s2 = dg8 >> 2, hi16d = dg8 & 3;
    int l = hi16d * 16 + l15k;
    float v = W[(size_t)d * 64 + k];
    ushort h = bf16rne(v);
    size_t idx = ((size_t)(s2 * 4 + mi) * 64 + l) * 8 + j;
    ws2[idx] = h;
    ws2[32768 + idx] = bf16rne(v - bf2f(h));
  }
}

// ---------------------------------------------------------------------------
// K1 (k2-clone structure): per (region, pc of 16 pixels): s^T = W^T * x.
// 2592 blocks x 256 thr (4 waves); wave w = mi (16 k-rows) for the block's
// 16 pixels. NO barriers / NO LDS in the d-loop: B-frag = 32B lane-contiguous
// x loads (imm offsets, L1-shared across the 4 waves); A-frag = contiguous
// short8 from fragment-major ws2 (L2-hot). 16 unrolled K=32 steps, 1 f32x4
// acc. Then cross-wave softmax over k via tiny LDS (3 barriers), a^T granule
// dump (2 f4-cols of the region slot) + per-(block,k) asum.
// ---------------------------------------------------------------------------
__global__ __launch_bounds__(256, 8) void k1_assign(
    const float* __restrict__ x, const ushort* __restrict__ ws2,
    float4* __restrict__ aT_ws, float* __restrict__ asum_ws) {
  __shared__ char sm[4608];
  ushort* atH = (ushort*)sm;              // [64 k][16 p]
  ushort* atL = (ushort*)(sm + 2048);
  float* smax = (float*)(sm + 4096);      // [4 w][16 p]
  float* ssum = (float*)(sm + 4352);

  int b = blockIdx.x;          // 2592 = 288 regions * 9 pixel-chunks
  int region = b / 9, pc = b % 9;
  int n = region / 9, r = region % 9;
  int y1 = (r / 3) * 12, x1 = (r % 3) * 12;
  int t = threadIdx.x;
  int w = t >> 6;              // = mi
  int lane = t & 63, l15 = lane & 15, hi16 = lane >> 4;
  const float* xn = x + (size_t)n * (36 * 36 * 512);

  // this lane's pixel row (B-frag: lane holds x[p=pc*16+l15][d=s*32+hi16*8+j])
  int p = pc * 16 + l15;
  const float* xrow =
      xn + ((size_t)(y1 + p / 12) * 36 + (x1 + p % 12)) * 512 + hi16 * 8;
  const ushort* aBase = ws2 + ((size_t)w * 64 + lane) * 8;  // + s2*2048 per step

  f32x4 acc = (f32x4){0.f, 0.f, 0.f, 0.f};

#pragma unroll
  for (int s = 0; s < 16; ++s) {
    const ushort* aPtr = aBase + (size_t)s * 2048;  // (s2*4+mi)*64*8 with mi=w
    short8 aH = *(const short8*)aPtr;
    short8 aL = *(const short8*)(aPtr + 32768);
    float4 v0 = *(const float4*)(xrow + s * 32);
    float4 v1 = *(const float4*)(xrow + s * 32 + 4);
    short8 bH, bL;
    cvt8hl(v0, v1, bH, bL);
    acc = mfma16(aH, bH, acc);
    acc = mfma16(aH, bL, acc);
    acc = mfma16(aL, bH, acc);
  }

  // ---- softmax over k (cross-wave: wave w holds k = w*16 + hi16*4 + rr) ----
  // acc[rr] = s[k][p = pc*16 + l15]
  {
    float m = fmaxf(fmaxf(acc[0], acc[1]), fmaxf(acc[2], acc[3]));
    m = fmaxf(m, __shfl_xor(m, 16));
    m = fmaxf(m, __shfl_xor(m, 32));
    if (hi16 == 0) smax[w * 16 + l15] = m;
  }
  __syncthreads();

  float e[4];
  {
    float M = fmaxf(fmaxf(smax[0 * 16 + l15], smax[1 * 16 + l15]),
                    fmaxf(smax[2 * 16 + l15], smax[3 * 16 + l15]));
    float s = 0.f;
#pragma unroll
    for (int rr = 0; rr < 4; ++rr) {
      e[rr] = __expf(acc[rr] - M);
      s += e[rr];
    }
    s += __shfl_xor(s, 16);
    s += __shfl_xor(s, 32);
    if (hi16 == 0) ssum[w * 16 + l15] = s;
  }
  __syncthreads();

  {
    float S = ssum[0 * 16 + l15] + ssum[1 * 16 + l15] + ssum[2 * 16 + l15] +
              ssum[3 * 16 + l15];
    float inv = 1.f / S;
#pragma unroll
    for (int rr = 0; rr < 4; ++rr) {
      float a = e[rr] * inv;
      int k = w * 16 + hi16 * 4 + rr;
      ushort h = bf16rne(a);
      atH[k * 16 + l15] = h;
      atL[k * 16 + l15] = bf16rne(a - bf2f(h));
      // asum partial over this block's 16 px -> slot (b, k)
      float s = a;
      s += __shfl_xor(s, 1);
      s += __shfl_xor(s, 2);
      s += __shfl_xor(s, 4);
      s += __shfl_xor(s, 8);
      if (l15 == 0) asum_ws[(size_t)b * 64 + k] = s;
    }
  }
  __syncthreads();

  // dump a^T granules: region slot [2][64][19 f4], this block owns f4-cols
  // pc*2 and pc*2+1 for all 64 rows. 256 f4 total, 1 per thread.
  {
    float4* dst = aT_ws + (size_t)region * 2432;
    int plane = t >> 7, rem = t & 127;
    int row = rem >> 1, g = rem & 1;
    float4 v = *(const float4*)(sm + plane * 2048 + row * 32 + g * 16);
    dst[plane * 1216 + row * 19 + pc * 2 + g] = v;
    if (pc == 8 && t < 128) {
      float4 z = {0.f, 0.f, 0.f, 0.f};
      int pl = t >> 6, rw = t & 63;
      dst[pl * 1216 + rw * 19 + 18] = z;
    }
  }
}

// ---------------------------------------------------------------------------
// K2: per (n,r,dc of 64): V = X^T * A - C*asum.  (unchanged except 9 asum
// slots per region now)
// ---------------------------------------------------------------------------
__global__ __launch_bounds__(512, 8) void k2_vlad(
    const float* __restrict__ x, const float* __restrict__ C,
    const float4* __restrict__ aT_ws, const float* __restrict__ asum_ws,
    float* __restrict__ out, float* __restrict__ colnorm) {
  __shared__ float4 smv[2504];               // 40064 B
  char* sm = (char*)smv;
  ushort* atH = (ushort*)sm;                 // [64 k][152 p]
  ushort* atL = (ushort*)(sm + 19456);
  int* poff = (int*)(sm + 38912);            // [160] pixel offsets (elements)
  float* asumS = (float*)(sm + 39552);
  float* cn2 = (float*)(sm + 39808);

  int b = blockIdx.x;          // 2304
  int reg = b % 288;           // XCD-swizzle: all 8 dc of a region -> same XCD
  int dc = b / 288;
  int n = reg / 9, r = reg % 9;
  int d0 = dc * 64;
  int y1 = (r / 3) * 12, x1 = (r % 3) * 12;
  int t = threadIdx.x;
  int w = t >> 6, lane = t & 63, l15 = lane & 15, hi16 = lane >> 4;
  const float* xn = x + (size_t)n * (36 * 36 * 512);

  if (t < 160) poff[t] = (t < 144) ? ((y1 + t / 12) * 36 + (x1 + t % 12)) * 512 : 0;
  if (t < 64) {
    float s = 0.f;
#pragma unroll
    for (int i = 0; i < 9; ++i) s += asum_ws[(size_t)(reg * 9 + i) * 64 + t];
    asumS[t] = s;
    cn2[t] = 0.f;
  }
  {
    const float4* src = aT_ws + (size_t)reg * 2432;
    for (int i = t; i < 2432; i += 512) smv[i] = src[i];
  }
  __syncthreads();

  int mi = w & 3, kh = w >> 2;
  int drow = d0 + mi * 16 + l15;
  const float* xcol = xn + drow;

  f32x4 acc[2];
  acc[0] = (f32x4){0.f, 0.f, 0.f, 0.f};
  acc[1] = (f32x4){0.f, 0.f, 0.f, 0.f};

#pragma unroll
  for (int ks = 0; ks < 5; ++ks) {
    int pb = ks * 32 + hi16 * 8;
    int4 poA = *reinterpret_cast<const int4*>(&poff[pb]);
    int4 poB = *reinterpret_cast<const int4*>(&poff[pb + 4]);
    float av[8];
    av[0] = xcol[poA.x]; av[1] = xcol[poA.y];
    av[2] = xcol[poA.z]; av[3] = xcol[poA.w];
    av[4] = xcol[poB.x]; av[5] = xcol[poB.y];
    av[6] = xcol[poB.z]; av[7] = xcol[poB.w];
    bool valid = (ks < 4) || (hi16 < 2);   // p >= 144 -> zero A (kills product)
    short8 ah, al;
#pragma unroll
    for (int j = 0; j < 8; ++j) {
      float v = valid ? av[j] : 0.f;
      ushort h = bf16rne(v);
      ah[j] = (short)h;
      al[j] = (short)bf16rne(v - bf2f(h));
    }
#pragma unroll
    for (int ni = 0; ni < 2; ++ni) {
      int row = kh * 32 + ni * 16 + l15;
      short8 bh = *(const short8*)(atH + row * 152 + pb);
      short8 bl = *(const short8*)(atL + row * 152 + pb);
      f32x4 a0 = acc[ni];
      a0 = mfma16(ah, bh, a0);
      a0 = mfma16(ah, bl, a0);
      a0 = mfma16(al, bh, a0);
      acc[ni] = a0;
    }
  }

  size_t obase = (size_t)reg * (512 * 64);
#pragma unroll
  for (int ni = 0; ni < 2; ++ni) {
    int k = kh * 32 + ni * 16 + l15;
    float ak = asumS[k];
    float s2 = 0.f;
#pragma unroll
    for (int rr = 0; rr < 4; ++rr) {
      int d = d0 + mi * 16 + hi16 * 4 + rr;
      float v = acc[ni][rr] - C[(size_t)d * 64 + k] * ak;
      out[obase + (size_t)d * 64 + k] = v;
      s2 += v * v;
    }
    atomicAdd(&cn2[k], s2);
  }
  __syncthreads();
  if (t < 64) colnorm[(size_t)(reg * 8 + dc) * 64 + t] = cn2[t];
}

// ---------------------------------------------------------------------------
// K3: intra-norm + global-norm scaling in place (sums 8 partial colnorms).
// ---------------------------------------------------------------------------
__global__ __launch_bounds__(256) void k3_scale(float* __restrict__ out,
                                                const float* __restrict__ colnorm) {
  int b = blockIdx.x;  // 1152
  int reg = b % 288;   // match k2's writer XCD for L2 reuse
  int dc = b / 288;

  __shared__ float ratio[64];
  __shared__ float fs[64];
  int t = threadIdx.x;
  float c = 0.f;
  if (t < 64) {
#pragma unroll
    for (int j = 0; j < 8; ++j) c += colnorm[(size_t)(reg * 8 + j) * 64 + t];
    ratio[t] = c / (c + EPSF);
  }
  __syncthreads();
  if (t < 64) {
    float g = 0.f;
#pragma unroll
    for (int j = 0; j < 64; ++j) g += ratio[j];
    fs[t] = rsqrtf(c + EPSF) * rsqrtf(g + EPSF);
  }
  __syncthreads();

  size_t base4 = (((size_t)reg * 512) + (size_t)dc * 128) * 64 / 4;
  float4* o4 = reinterpret_cast<float4*>(out);
  for (int j = 0; j < 8; ++j) {
    size_t idx = base4 + t + 256 * j;
    float4 v = o4[idx];
    int k0 = (int)((idx * 4) & 63);
    v.x *= fs[k0]; v.y *= fs[k0 + 1]; v.z *= fs[k0 + 2]; v.w *= fs[k0 + 3];
    o4[idx] = v;
  }
}

extern "C" void kernel_launch(void* const* d_in, const int* in_sizes, int n_in,
                              void* d_out, int out_size, void* d_ws, size_t ws_size,
                              hipStream_t stream) {
  const float* x = (const float*)d_in[0];   // [32,36,36,512]
  const float* Wc = (const float*)d_in[1];  // [512,64]
  const float* C = (const float*)d_in[2];   // [512,64]
  float* out = (float*)d_out;

  char* ws = (char*)d_ws;
  ushort* ws2 = (ushort*)(ws);              // 131072 B (2 x 64KB planes)
  float* asum_ws = (float*)(ws + 131072);   // 2592*64*4 = 663552 B
  float* colnorm = (float*)(ws + 794624);   // 2304*64*4 = 589824 B
  float4* aT_ws = (float4*)(ws + 1384448);  // 288 * 38912 B = 11.2 MB

  k0_wt<<<64, 256, 0, stream>>>(Wc, ws2);
  k1_assign<<<2592, 256, 0, stream>>>(x, ws2, aT_ws, asum_ws);
  k2_vlad<<<2304, 512, 0, stream>>>(x, C, aT_ws, asum_ws, out, colnorm);
  k3_scale<<<1152, 256, 0, stream>>>(out, colnorm);
}

// Round 12
// 105.308 us; speedup vs baseline: 1.0352x; 1.0352x over previous
//
#include <hip/hip_runtime.h>

typedef __attribute__((ext_vector_type(4))) float f32x4;
typedef __attribute__((ext_vector_type(8))) short short8;

#define EPSF 1e-12f

__device__ __forceinline__ ushort bf16rne(float x) {
  uint u = __float_as_uint(x);
  u += 0x7fffu + ((u >> 16) & 1u);
  return (ushort)(u >> 16);
}
__device__ __forceinline__ float bf2f(ushort h) {
  return __uint_as_float(((uint)h) << 16);
}
__device__ __forceinline__ f32x4 mfma16(short8 a, short8 b, f32x4 c) {
  return __builtin_amdgcn_mfma_f32_16x16x32_bf16(a, b, c, 0, 0, 0);
}

// ---------------------------------------------------------------------------
// K0: W [512][64] f32 -> fragment-major W^T bf16 hi/lo:
//   ws2[plane][s2][mi][lane l][j]: element = W^T(k=mi*16+(l&15), d=s2*32+(l>>4)*8+j)
// so a k1 wave's A-frag is ONE contiguous 1KB short8 load. plane stride 32768 u16.
// ---------------------------------------------------------------------------
__global__ __launch_bounds__(256) void k0_wt(const float* __restrict__ W,
                                             ushort* __restrict__ ws2) {
  int k = blockIdx.x;  // 64
  int mi = k >> 4, l15k = k & 15;
  for (int task = threadIdx.x; task < 512; task += 256) {
    int dg8 = task >> 3, j = task & 7;   // dg8 = d>>3
    int d = dg8 * 8 + j;
    int s2 = dg8 >> 2, hi16d = dg8 & 3;
    int l = hi16d * 16 + l15k;
    float v = W[(size_t)d * 64 + k];
    ushort h = bf16rne(v);
    size_t idx = ((size_t)(s2 * 4 + mi) * 64 + l) * 8 + j;
    ws2[idx] = h;
    ws2[32768 + idx] = bf16rne(v - bf2f(h));
  }
}

// ---------------------------------------------------------------------------
// K1: one block per (n, image row y) -- 1152 blocks x 256 thr (4 waves).
// Reads its 72KB x-row CONTIGUOUSLY (memory-order; regions decoded only at
// the a^T write). Stage: f32 -> bf16 hi/lo LDS image [36 p][512 d] with
// granule-XOR swizzle (one-time conversion). Then barrier-free 16-step MFMA
// (A = fragment-major ws2, L2-hot; B = swizzled ds_read, 2-way free).
// Cross-wave softmax over k; a^T u16 dump into region slots + per-(row,col)
// asum slots. LDS 75264 B dynamic -> 2 blocks/CU.
// ---------------------------------------------------------------------------
__global__ __launch_bounds__(256, 2) void k1_assign(
    const float* __restrict__ x, const ushort* __restrict__ ws2,
    ushort* __restrict__ aTu, float* __restrict__ asum_ws) {
  extern __shared__ char sm[];
  ushort* xH = (ushort*)sm;               // [36][512] u16
  ushort* xL = (ushort*)(sm + 36864);
  ushort* atH = (ushort*)sm;              // overlay after MFMA: [64 k][48 p]
  ushort* atL = (ushort*)(sm + 6144);
  float* smax = (float*)(sm + 73728);     // [4 w][48 p]
  float* ssum = (float*)(sm + 74496);

  int b = blockIdx.x;  // 1152 = 32 n * 36 y
  int n = b / 36, y = b % 36;
  int t = threadIdx.x;
  int w = t >> 6, lane = t & 63, l15 = lane & 15, hi16 = lane >> 4;
  const float* xn = x + (size_t)n * (36 * 36 * 512);
  const float4* xr4 = (const float4*)(xn + (size_t)y * (36 * 512));

  // ---- stage full row (72KB contiguous read) -> bf16 hi/lo LDS image ----
  // task = p*128 + q (q = float4 index along d): granule g=q>>1, half=q&1,
  // swizzled column sg = g ^ (p&7).
#pragma unroll
  for (int bb = 0; bb < 3; ++bb) {
    float4 vv[6];
#pragma unroll
    for (int j = 0; j < 6; ++j) vv[j] = xr4[t + (bb * 6 + j) * 256];
#pragma unroll
    for (int j = 0; j < 6; ++j) {
      int task = t + (bb * 6 + j) * 256;
      int p = task >> 7, q = task & 127;
      int sg = (q >> 1) ^ (p & 7);
      int off = p * 512 + sg * 8 + (q & 1) * 4;
      float4 v = vv[j];
      ushort h0 = bf16rne(v.x), h1 = bf16rne(v.y), h2 = bf16rne(v.z), h3 = bf16rne(v.w);
      uint2 hp, lp;
      hp.x = (uint)h0 | ((uint)h1 << 16);
      hp.y = (uint)h2 | ((uint)h3 << 16);
      lp.x = (uint)bf16rne(v.x - bf2f(h0)) | ((uint)bf16rne(v.y - bf2f(h1)) << 16);
      lp.y = (uint)bf16rne(v.z - bf2f(h2)) | ((uint)bf16rne(v.w - bf2f(h3)) << 16);
      *(uint2*)(xH + off) = hp;
      *(uint2*)(xL + off) = lp;
    }
  }
  __syncthreads();

  // ---- MFMA: s^T = W^T * x (36 real pixel cols, 48 computed) ----
  f32x4 acc[3];
#pragma unroll
  for (int ni = 0; ni < 3; ++ni) acc[ni] = (f32x4){0.f, 0.f, 0.f, 0.f};

#pragma unroll 4
  for (int s = 0; s < 16; ++s) {
    const ushort* aPtr = ws2 + ((size_t)(s * 4 + w) * 64 + lane) * 8;
    short8 aH = *(const short8*)aPtr;
    short8 aL = *(const short8*)(aPtr + 32768);
#pragma unroll
    for (int ni = 0; ni < 3; ++ni) {
      int p = ni * 16 + l15;
      int pr = (p < 36) ? p : (p - 36);   // junk cols reuse valid rows (finite)
      int sg = (s * 4 + hi16) ^ (pr & 7);
      const ushort* bp = xH + pr * 512 + sg * 8;
      short8 bH = *(const short8*)bp;
      short8 bL = *(const short8*)(bp + 36864 / 2);
      f32x4 a0 = acc[ni];
      a0 = mfma16(aH, bH, a0);
      a0 = mfma16(aH, bL, a0);
      a0 = mfma16(aL, bH, a0);
      acc[ni] = a0;
    }
  }
  __syncthreads();  // x-image dead; overlays safe after following barriers

  // ---- softmax over k (wave w holds k = w*16 + hi16*4 + rr; col p) ----
  float lm[3];
#pragma unroll
  for (int ni = 0; ni < 3; ++ni) {
    float m = fmaxf(fmaxf(acc[ni][0], acc[ni][1]), fmaxf(acc[ni][2], acc[ni][3]));
    m = fmaxf(m, __shfl_xor(m, 16));
    m = fmaxf(m, __shfl_xor(m, 32));
    lm[ni] = m;
  }
  if (hi16 == 0)
#pragma unroll
    for (int ni = 0; ni < 3; ++ni) smax[w * 48 + ni * 16 + l15] = lm[ni];
  __syncthreads();

  float e[3][4], ls[3];
#pragma unroll
  for (int ni = 0; ni < 3; ++ni) {
    int p = ni * 16 + l15;
    float M = fmaxf(fmaxf(smax[0 * 48 + p], smax[1 * 48 + p]),
                    fmaxf(smax[2 * 48 + p], smax[3 * 48 + p]));
    float s = 0.f;
#pragma unroll
    for (int rr = 0; rr < 4; ++rr) {
      e[ni][rr] = __expf(acc[ni][rr] - M);
      s += e[ni][rr];
    }
    s += __shfl_xor(s, 16);
    s += __shfl_xor(s, 32);
    ls[ni] = s;
  }
  if (hi16 == 0)
#pragma unroll
    for (int ni = 0; ni < 3; ++ni) ssum[w * 48 + ni * 16 + l15] = ls[ni];
  __syncthreads();

#pragma unroll
  for (int ni = 0; ni < 3; ++ni) {
    int p = ni * 16 + l15;
    if (p < 36) {
      float S = ssum[0 * 48 + p] + ssum[1 * 48 + p] + ssum[2 * 48 + p] + ssum[3 * 48 + p];
      float inv = 1.f / S;
#pragma unroll
      for (int rr = 0; rr < 4; ++rr) {
        float a = e[ni][rr] * inv;
        int k = w * 16 + hi16 * 4 + rr;
        ushort h = bf16rne(a);
        atH[k * 48 + p] = h;
        atL[k * 48 + p] = bf16rne(a - bf2f(h));
      }
    }
  }
  __syncthreads();

  // ---- asum per (region-col, k): 12-px sums -> slot (b, col) ----
  if (t < 192) {
    int col = t >> 6, k = t & 63;
    float s = 0.f;
#pragma unroll
    for (int xi = 0; xi < 12; ++xi) {
      int idx = k * 48 + col * 12 + xi;
      s += bf2f(atH[idx]) + bf2f(atL[idx]);
    }
    asum_ws[((size_t)b * 3 + col) * 64 + k] = s;
  }

  // ---- dump a^T u16 into the 3 touched region slots ----
  // region slot = [2 planes (9728 u16)][64 k (152 u16)][p-local]
  {
    int q = t >> 1, half = t & 1;
    int plane = q >> 6, k = q & 63;
    const ushort* src = (plane ? atL : atH) + k * 48;
    int ry = y / 12, prow = y % 12;
    size_t base0 = (size_t)(n * 9 + ry * 3) * 19456 + (size_t)plane * 9728 +
                   (size_t)k * 152 + prow * 12;
#pragma unroll
    for (int i = 0; i < 18; ++i) {
      int px = half * 18 + i;
      int col = px / 12, xi = px - col * 12;
      aTu[base0 + (size_t)col * 19456 + xi] = src[px];
    }
  }
}

// ---------------------------------------------------------------------------
// K2: per (n,r,dc of 64): V = X^T * A - C*asum.  (asum now from 12 row-slots)
// ---------------------------------------------------------------------------
__global__ __launch_bounds__(512, 8) void k2_vlad(
    const float* __restrict__ x, const float* __restrict__ C,
    const float4* __restrict__ aT_ws, const float* __restrict__ asum_ws,
    float* __restrict__ out, float* __restrict__ colnorm) {
  __shared__ float4 smv[2504];               // 40064 B
  char* sm = (char*)smv;
  ushort* atH = (ushort*)sm;                 // [64 k][152 p]
  ushort* atL = (ushort*)(sm + 19456);
  int* poff = (int*)(sm + 38912);            // [160] pixel offsets (elements)
  float* asumS = (float*)(sm + 39552);
  float* cn2 = (float*)(sm + 39808);

  int b = blockIdx.x;          // 2304
  int reg = b % 288;           // XCD-swizzle: all 8 dc of a region -> same XCD
  int dc = b / 288;
  int n = reg / 9, r = reg % 9;
  int d0 = dc * 64;
  int y1 = (r / 3) * 12, x1 = (r % 3) * 12;
  int t = threadIdx.x;
  int w = t >> 6, lane = t & 63, l15 = lane & 15, hi16 = lane >> 4;
  const float* xn = x + (size_t)n * (36 * 36 * 512);

  if (t < 160) poff[t] = (t < 144) ? ((y1 + t / 12) * 36 + (x1 + t % 12)) * 512 : 0;
  if (t < 64) {
    int ry = r / 3, rc = r % 3;
    float s = 0.f;
#pragma unroll
    for (int j = 0; j < 12; ++j)
      s += asum_ws[((size_t)(n * 36 + ry * 12 + j) * 3 + rc) * 64 + t];
    asumS[t] = s;
    cn2[t] = 0.f;
  }
  {
    const float4* src = aT_ws + (size_t)reg * 2432;
    for (int i = t; i < 2432; i += 512) smv[i] = src[i];
  }
  __syncthreads();

  int mi = w & 3, kh = w >> 2;
  int drow = d0 + mi * 16 + l15;
  const float* xcol = xn + drow;

  f32x4 acc[2];
  acc[0] = (f32x4){0.f, 0.f, 0.f, 0.f};
  acc[1] = (f32x4){0.f, 0.f, 0.f, 0.f};

#pragma unroll
  for (int ks = 0; ks < 5; ++ks) {
    int pb = ks * 32 + hi16 * 8;
    int4 poA = *reinterpret_cast<const int4*>(&poff[pb]);
    int4 poB = *reinterpret_cast<const int4*>(&poff[pb + 4]);
    float av[8];
    av[0] = xcol[poA.x]; av[1] = xcol[poA.y];
    av[2] = xcol[poA.z]; av[3] = xcol[poA.w];
    av[4] = xcol[poB.x]; av[5] = xcol[poB.y];
    av[6] = xcol[poB.z]; av[7] = xcol[poB.w];
    bool valid = (ks < 4) || (hi16 < 2);   // p >= 144 -> zero A (kills product)
    short8 ah, al;
#pragma unroll
    for (int j = 0; j < 8; ++j) {
      float v = valid ? av[j] : 0.f;
      ushort h = bf16rne(v);
      ah[j] = (short)h;
      al[j] = (short)bf16rne(v - bf2f(h));
    }
#pragma unroll
    for (int ni = 0; ni < 2; ++ni) {
      int row = kh * 32 + ni * 16 + l15;
      short8 bh = *(const short8*)(atH + row * 152 + pb);
      short8 bl = *(const short8*)(atL + row * 152 + pb);
      f32x4 a0 = acc[ni];
      a0 = mfma16(ah, bh, a0);
      a0 = mfma16(ah, bl, a0);
      a0 = mfma16(al, bh, a0);
      acc[ni] = a0;
    }
  }

  size_t obase = (size_t)reg * (512 * 64);
#pragma unroll
  for (int ni = 0; ni < 2; ++ni) {
    int k = kh * 32 + ni * 16 + l15;
    float ak = asumS[k];
    float s2 = 0.f;
#pragma unroll
    for (int rr = 0; rr < 4; ++rr) {
      int d = d0 + mi * 16 + hi16 * 4 + rr;
      float v = acc[ni][rr] - C[(size_t)d * 64 + k] * ak;
      out[obase + (size_t)d * 64 + k] = v;
      s2 += v * v;
    }
    atomicAdd(&cn2[k], s2);
  }
  __syncthreads();
  if (t < 64) colnorm[(size_t)(reg * 8 + dc) * 64 + t] = cn2[t];
}

// ---------------------------------------------------------------------------
// K3: intra-norm + global-norm scaling in place (sums 8 partial colnorms).
// ---------------------------------------------------------------------------
__global__ __launch_bounds__(256) void k3_scale(float* __restrict__ out,
                                                const float* __restrict__ colnorm) {
  int b = blockIdx.x;  // 1152
  int reg = b % 288;   // match k2's writer XCD for L2 reuse
  int dc = b / 288;

  __shared__ float ratio[64];
  __shared__ float fs[64];
  int t = threadIdx.x;
  float c = 0.f;
  if (t < 64) {
#pragma unroll
    for (int j = 0; j < 8; ++j) c += colnorm[(size_t)(reg * 8 + j) * 64 + t];
    ratio[t] = c / (c + EPSF);
  }
  __syncthreads();
  if (t < 64) {
    float g = 0.f;
#pragma unroll
    for (int j = 0; j < 64; ++j) g += ratio[j];
    fs[t] = rsqrtf(c + EPSF) * rsqrtf(g + EPSF);
  }
  __syncthreads();

  size_t base4 = (((size_t)reg * 512) + (size_t)dc * 128) * 64 / 4;
  float4* o4 = reinterpret_cast<float4*>(out);
  for (int j = 0; j < 8; ++j) {
    size_t idx = base4 + t + 256 * j;
    float4 v = o4[idx];
    int k0 = (int)((idx * 4) & 63);
    v.x *= fs[k0]; v.y *= fs[k0 + 1]; v.z *= fs[k0 + 2]; v.w *= fs[k0 + 3];
    o4[idx] = v;
  }
}

extern "C" void kernel_launch(void* const* d_in, const int* in_sizes, int n_in,
                              void* d_out, int out_size, void* d_ws, size_t ws_size,
                              hipStream_t stream) {
  const float* x = (const float*)d_in[0];   // [32,36,36,512]
  const float* Wc = (const float*)d_in[1];  // [512,64]
  const float* C = (const float*)d_in[2];   // [512,64]
  float* out = (float*)d_out;

  char* ws = (char*)d_ws;
  ushort* ws2 = (ushort*)(ws);              // 131072 B (2 x 64KB planes)
  float* asum_ws = (float*)(ws + 131072);   // 1152*3*64*4 = 884736 B
  float* colnorm = (float*)(ws + 1015808);  // 2304*64*4 = 589824 B
  char* aT_base = ws + 1605632;             // 288 * 38912 B = 11.2 MB

  k0_wt<<<64, 256, 0, stream>>>(Wc, ws2);
  hipFuncSetAttribute((const void*)k1_assign,
                      hipFuncAttributeMaxDynamicSharedMemorySize, 75264);
  k1_assign<<<1152, 256, 75264, stream>>>(x, ws2, (ushort*)aT_base, asum_ws);
  k2_vlad<<<2304, 512, 0, stream>>>(x, C, (const float4*)aT_base, asum_ws, out, colnorm);
  k3_scale<<<1152, 256, 0, stream>>>(out, colnorm);
}

// Round 13
// 92.905 us; speedup vs baseline: 1.1734x; 1.1335x over previous
//
#include <hip/hip_runtime.h>

typedef __attribute__((ext_vector_type(4))) float f32x4;
typedef __attribute__((ext_vector_type(8))) short short8;

#define EPSF 1e-12f

__device__ __forceinline__ ushort bf16rne(float x) {
  uint u = __float_as_uint(x);
  u += 0x7fffu + ((u >> 16) & 1u);
  return (ushort)(u >> 16);
}
__device__ __forceinline__ float bf2f(ushort h) {
  return __uint_as_float(((uint)h) << 16);
}
__device__ __forceinline__ f32x4 mfma16(short8 a, short8 b, f32x4 c) {
  return __builtin_amdgcn_mfma_f32_16x16x32_bf16(a, b, c, 0, 0, 0);
}

// ---------------------------------------------------------------------------
// K0: W [512][64] f32 -> fragment-major W^T bf16 hi/lo:
//   ws2[plane][s2][mi][lane l][j]: element = W^T(k=mi*16+(l&15), d=s2*32+(l>>4)*8+j)
// so a k1 wave's A-frag is ONE contiguous 1KB short8 load. plane stride 32768 u16.
// ---------------------------------------------------------------------------
__global__ __launch_bounds__(256) void k0_wt(const float* __restrict__ W,
                                             ushort* __restrict__ ws2) {
  int k = blockIdx.x;  // 64
  int mi = k >> 4, l15k = k & 15;
  for (int task = threadIdx.x; task < 512; task += 256) {
    int dg8 = task >> 3, j = task & 7;   // dg8 = d>>3
    int d = dg8 * 8 + j;
    int s2 = dg8 >> 2, hi16d = dg8 & 3;
    int l = hi16d * 16 + l15k;
    float v = W[(size_t)d * 64 + k];
    ushort h = bf16rne(v);
    size_t idx = ((size_t)(s2 * 4 + mi) * 64 + l) * 8 + j;
    ws2[idx] = h;
    ws2[32768 + idx] = bf16rne(v - bf2f(h));
  }
}

// ---------------------------------------------------------------------------
// K1 (single-barrier cell kernel): block = one (region, row) cell of 12
// contiguous pixels. 3456 blocks x 256 thr (4 waves, wave = mi = 16 k-rows).
// Stage: 6 independent coalesced f4 loads/thread (24KB x, memory order) ->
// bf16 hi/lo -> swizzled ds_write (row stride 520 u16: granule-XOR + bank
// de-alias). ONE barrier. 16 MFMA steps, NO barriers (A = contiguous short8
// ws2, L2-hot; B = swizzled ds_read). Cross-wave softmax (2 small barriers),
// direct u16 a^T dump into k2-ready region slot + per-cell asum.
// LDS 25472 B -> 6 blocks/CU = 24 waves/CU; 13.5 blocks/CU queued.
// ---------------------------------------------------------------------------
__global__ __launch_bounds__(256, 6) void k1_assign(
    const float* __restrict__ x, const ushort* __restrict__ ws2,
    ushort* __restrict__ aTu, float* __restrict__ asum_ws) {
  __shared__ char sm[25472];
  ushort* xH = (ushort*)sm;               // [12 p][520 u16] (content cols 0..511)
  ushort* xL = (ushort*)(sm + 12480);     // u16 offset 6240 from xH
  float* smax = (float*)(sm + 24960);     // [4 w][16 p]
  float* ssum = (float*)(sm + 25216);

  int b = blockIdx.x;  // 3456 = 32 n * 36 y * 3 col
  int n = b / 108, rem = b % 108;
  int y = rem / 3, col = rem % 3;
  int t = threadIdx.x;
  int w = t >> 6, lane = t & 63, l15 = lane & 15, hi16 = lane >> 4;
  const float4* xb4 =
      (const float4*)(x + ((size_t)n * 1296 + y * 36 + col * 12) * 512);

  // ---- stage: 1536 f4 tasks, 6 per thread, all independent ----
  float4 stg[6];
#pragma unroll
  for (int i = 0; i < 6; ++i) stg[i] = xb4[t + i * 256];
#pragma unroll
  for (int i = 0; i < 6; ++i) {
    int idx = t + i * 256;
    int p = idx >> 7, q = idx & 127;      // p: pixel 0..11, q: f4 along d
    int gp = (q >> 1) ^ (p & 7);          // content granule q>>1 -> phys slot
    int off = p * 520 + gp * 8 + (q & 1) * 4;
    float4 v = stg[i];
    ushort h0 = bf16rne(v.x), h1 = bf16rne(v.y), h2 = bf16rne(v.z), h3 = bf16rne(v.w);
    uint2 hp, lp;
    hp.x = (uint)h0 | ((uint)h1 << 16);
    hp.y = (uint)h2 | ((uint)h3 << 16);
    lp.x = (uint)bf16rne(v.x - bf2f(h0)) | ((uint)bf16rne(v.y - bf2f(h1)) << 16);
    lp.y = (uint)bf16rne(v.z - bf2f(h2)) | ((uint)bf16rne(v.w - bf2f(h3)) << 16);
    *(uint2*)(xH + off) = hp;
    *(uint2*)(xL + off) = lp;
  }
  __syncthreads();   // the ONLY staging barrier

  // ---- 16 MFMA steps, barrier-free ----
  int pr = (l15 < 12) ? l15 : 0;          // junk cols read row 0 (discarded)
  f32x4 acc = (f32x4){0.f, 0.f, 0.f, 0.f};
#pragma unroll
  for (int s = 0; s < 16; ++s) {
    const ushort* aPtr = ws2 + ((size_t)(s * 4 + w) * 64 + lane) * 8;
    short8 aH = *(const short8*)aPtr;
    short8 aL = *(const short8*)(aPtr + 32768);
    int g = s * 4 + hi16;
    const ushort* bp = xH + pr * 520 + ((g ^ (pr & 7)) << 3);
    short8 bH = *(const short8*)bp;
    short8 bL = *(const short8*)(bp + 6240);
    acc = mfma16(aH, bH, acc);
    acc = mfma16(aH, bL, acc);
    acc = mfma16(aL, bH, acc);
  }

  // ---- softmax over k (wave w holds k = w*16 + hi16*4 + rr; col p = l15) ----
  {
    float m = fmaxf(fmaxf(acc[0], acc[1]), fmaxf(acc[2], acc[3]));
    m = fmaxf(m, __shfl_xor(m, 16));
    m = fmaxf(m, __shfl_xor(m, 32));
    if (hi16 == 0) smax[w * 16 + l15] = m;
  }
  __syncthreads();
  float e[4];
  {
    float M = fmaxf(fmaxf(smax[0 * 16 + l15], smax[1 * 16 + l15]),
                    fmaxf(smax[2 * 16 + l15], smax[3 * 16 + l15]));
    float s = 0.f;
#pragma unroll
    for (int rr = 0; rr < 4; ++rr) {
      e[rr] = __expf(acc[rr] - M);
      s += e[rr];
    }
    s += __shfl_xor(s, 16);
    s += __shfl_xor(s, 32);
    if (hi16 == 0) ssum[w * 16 + l15] = s;
  }
  __syncthreads();
  float S = ssum[0 * 16 + l15] + ssum[1 * 16 + l15] + ssum[2 * 16 + l15] +
            ssum[3 * 16 + l15];
  float inv = 1.f / S;

  // ---- asum (per cell, per k) + direct a^T dump into region slot ----
  int region = n * 9 + (y / 12) * 3 + col;
  int prow = y % 12;
  size_t slot = (size_t)region * 19456;
  float av[4];
#pragma unroll
  for (int rr = 0; rr < 4; ++rr) {
    float a = (l15 < 12) ? e[rr] * inv : 0.f;
    av[rr] = a;
    float s = a;
    s += __shfl_xor(s, 1);
    s += __shfl_xor(s, 2);
    s += __shfl_xor(s, 4);
    s += __shfl_xor(s, 8);
    if (l15 == 0) asum_ws[(size_t)b * 64 + w * 16 + hi16 * 4 + rr] = s;
  }
  if (l15 < 12) {
#pragma unroll
    for (int rr = 0; rr < 4; ++rr) {
      int k = w * 16 + hi16 * 4 + rr;
      ushort h = bf16rne(av[rr]);
      aTu[slot + (size_t)k * 152 + prow * 12 + l15] = h;
      aTu[slot + 9728 + (size_t)k * 152 + prow * 12 + l15] =
          bf16rne(av[rr] - bf2f(h));
    }
  }
  // zero pad u16 cols 144..151 (one cell per region does it)
  if (prow == 11 && col == 2) {
    int plane = t >> 7, kk = (t >> 1) & 63, half = t & 1;
    uint2 z; z.x = 0u; z.y = 0u;
    *(uint2*)(aTu + slot + (size_t)plane * 9728 + (size_t)kk * 152 + 144 + half * 4) = z;
  }
}

// ---------------------------------------------------------------------------
// K2: per (n,r,dc of 64): V = X^T * A - C*asum.  (asum now from 12 cell-slots)
// ---------------------------------------------------------------------------
__global__ __launch_bounds__(512, 8) void k2_vlad(
    const float* __restrict__ x, const float* __restrict__ C,
    const float4* __restrict__ aT_ws, const float* __restrict__ asum_ws,
    float* __restrict__ out, float* __restrict__ colnorm) {
  __shared__ float4 smv[2504];               // 40064 B
  char* sm = (char*)smv;
  ushort* atH = (ushort*)sm;                 // [64 k][152 p]
  ushort* atL = (ushort*)(sm + 19456);
  int* poff = (int*)(sm + 38912);            // [160] pixel offsets (elements)
  float* asumS = (float*)(sm + 39552);
  float* cn2 = (float*)(sm + 39808);

  int b = blockIdx.x;          // 2304
  int reg = b % 288;           // XCD-swizzle: all 8 dc of a region -> same XCD
  int dc = b / 288;
  int n = reg / 9, r = reg % 9;
  int d0 = dc * 64;
  int y1 = (r / 3) * 12, x1 = (r % 3) * 12;
  int t = threadIdx.x;
  int w = t >> 6, lane = t & 63, l15 = lane & 15, hi16 = lane >> 4;
  const float* xn = x + (size_t)n * (36 * 36 * 512);

  if (t < 160) poff[t] = (t < 144) ? ((y1 + t / 12) * 36 + (x1 + t % 12)) * 512 : 0;
  if (t < 64) {
    int ry = r / 3, rc = r % 3;
    float s = 0.f;
#pragma unroll
    for (int j = 0; j < 12; ++j)
      s += asum_ws[(size_t)(n * 108 + (ry * 12 + j) * 3 + rc) * 64 + t];
    asumS[t] = s;
    cn2[t] = 0.f;
  }
  {
    const float4* src = aT_ws + (size_t)reg * 2432;
    for (int i = t; i < 2432; i += 512) smv[i] = src[i];
  }
  __syncthreads();

  int mi = w & 3, kh = w >> 2;
  int drow = d0 + mi * 16 + l15;
  const float* xcol = xn + drow;

  f32x4 acc[2];
  acc[0] = (f32x4){0.f, 0.f, 0.f, 0.f};
  acc[1] = (f32x4){0.f, 0.f, 0.f, 0.f};

#pragma unroll
  for (int ks = 0; ks < 5; ++ks) {
    int pb = ks * 32 + hi16 * 8;
    int4 poA = *reinterpret_cast<const int4*>(&poff[pb]);
    int4 poB = *reinterpret_cast<const int4*>(&poff[pb + 4]);
    float av[8];
    av[0] = xcol[poA.x]; av[1] = xcol[poA.y];
    av[2] = xcol[poA.z]; av[3] = xcol[poA.w];
    av[4] = xcol[poB.x]; av[5] = xcol[poB.y];
    av[6] = xcol[poB.z]; av[7] = xcol[poB.w];
    bool valid = (ks < 4) || (hi16 < 2);   // p >= 144 -> zero A (kills product)
    short8 ah, al;
#pragma unroll
    for (int j = 0; j < 8; ++j) {
      float v = valid ? av[j] : 0.f;
      ushort h = bf16rne(v);
      ah[j] = (short)h;
      al[j] = (short)bf16rne(v - bf2f(h));
    }
#pragma unroll
    for (int ni = 0; ni < 2; ++ni) {
      int row = kh * 32 + ni * 16 + l15;
      short8 bh = *(const short8*)(atH + row * 152 + pb);
      short8 bl = *(const short8*)(atL + row * 152 + pb);
      f32x4 a0 = acc[ni];
      a0 = mfma16(ah, bh, a0);
      a0 = mfma16(ah, bl, a0);
      a0 = mfma16(al, bh, a0);
      acc[ni] = a0;
    }
  }

  size_t obase = (size_t)reg * (512 * 64);
#pragma unroll
  for (int ni = 0; ni < 2; ++ni) {
    int k = kh * 32 + ni * 16 + l15;
    float ak = asumS[k];
    float s2 = 0.f;
#pragma unroll
    for (int rr = 0; rr < 4; ++rr) {
      int d = d0 + mi * 16 + hi16 * 4 + rr;
      float v = acc[ni][rr] - C[(size_t)d * 64 + k] * ak;
      out[obase + (size_t)d * 64 + k] = v;
      s2 += v * v;
    }
    atomicAdd(&cn2[k], s2);
  }
  __syncthreads();
  if (t < 64) colnorm[(size_t)(reg * 8 + dc) * 64 + t] = cn2[t];
}

// ---------------------------------------------------------------------------
// K3: intra-norm + global-norm scaling in place (sums 8 partial colnorms).
// ---------------------------------------------------------------------------
__global__ __launch_bounds__(256) void k3_scale(float* __restrict__ out,
                                                const float* __restrict__ colnorm) {
  int b = blockIdx.x;  // 1152
  int reg = b % 288;   // match k2's writer XCD for L2 reuse
  int dc = b / 288;

  __shared__ float ratio[64];
  __shared__ float fs[64];
  int t = threadIdx.x;
  float c = 0.f;
  if (t < 64) {
#pragma unroll
    for (int j = 0; j < 8; ++j) c += colnorm[(size_t)(reg * 8 + j) * 64 + t];
    ratio[t] = c / (c + EPSF);
  }
  __syncthreads();
  if (t < 64) {
    float g = 0.f;
#pragma unroll
    for (int j = 0; j < 64; ++j) g += ratio[j];
    fs[t] = rsqrtf(c + EPSF) * rsqrtf(g + EPSF);
  }
  __syncthreads();

  size_t base4 = (((size_t)reg * 512) + (size_t)dc * 128) * 64 / 4;
  float4* o4 = reinterpret_cast<float4*>(out);
  for (int j = 0; j < 8; ++j) {
    size_t idx = base4 + t + 256 * j;
    float4 v = o4[idx];
    int k0 = (int)((idx * 4) & 63);
    v.x *= fs[k0]; v.y *= fs[k0 + 1]; v.z *= fs[k0 + 2]; v.w *= fs[k0 + 3];
    o4[idx] = v;
  }
}

extern "C" void kernel_launch(void* const* d_in, const int* in_sizes, int n_in,
                              void* d_out, int out_size, void* d_ws, size_t ws_size,
                              hipStream_t stream) {
  const float* x = (const float*)d_in[0];   // [32,36,36,512]
  const float* Wc = (const float*)d_in[1];  // [512,64]
  const float* C = (const float*)d_in[2];   // [512,64]
  float* out = (float*)d_out;

  char* ws = (char*)d_ws;
  ushort* ws2 = (ushort*)(ws);              // 131072 B (2 x 64KB planes)
  float* asum_ws = (float*)(ws + 131072);   // 3456*64*4 = 884736 B
  float* colnorm = (float*)(ws + 1015808);  // 2304*64*4 = 589824 B
  char* aT_base = ws + 1605632;             // 288 * 38912 B = 11.2 MB

  k0_wt<<<64, 256, 0, stream>>>(Wc, ws2);
  k1_assign<<<3456, 256, 0, stream>>>(x, ws2, (ushort*)aT_base, asum_ws);
  k2_vlad<<<2304, 512, 0, stream>>>(x, C, (const float4*)aT_base, asum_ws, out, colnorm);
  k3_scale<<<1152, 256, 0, stream>>>(out, colnorm);
}